// Round 5
// baseline (146.634 us; speedup 1.0000x reference)
//
#include <hip/hip_runtime.h>

#define B_ 8
#define C_ 128
#define H_ 64
#define W_ 64
#define O_ 128
#define F_ 18
#define K2_ 9
#define HW_ 4096
#define CK2_ 1152

typedef __attribute__((ext_vector_type(8))) short short8_t;   // 8 bf16
typedef __attribute__((ext_vector_type(4))) float f32x4_t;

__device__ inline short bf16r(float f) {
  unsigned u = __builtin_bit_cast(unsigned, f);
  u += 0x7FFFu + ((u >> 16) & 1u);     // round-to-nearest-even
  return (short)(u >> 16);
}
__device__ inline float bf2f(short s) {
  unsigned u = ((unsigned)(unsigned short)s) << 16;
  return __builtin_bit_cast(float, u);
}

// ---------------- merged prep: w repack | w_off repack | x transpose --------
// blocks [0,576): w -> w_bt[o][kk], kk = tap*128+c
// blocks [576,720): w_off -> w_ot[32][kk] (rows 18..31 zero)
// blocks [720,1232): x NCHW f32 -> x_t[b][y][x][c] bf16
__global__ __launch_bounds__(256) void prep_all_kernel(
    const float* __restrict__ w, const float* __restrict__ w_off,
    const float* __restrict__ x,
    short* __restrict__ w_bt, short* __restrict__ w_ot,
    short* __restrict__ x_t) {
  __shared__ float tile[128][65];
  int bid = blockIdx.x, t = threadIdx.x;
  if (bid < 576) {
    int i = bid * 256 + t;
    if (i < O_ * CK2_) {
      int o = i / CK2_, r = i % CK2_;
      int kt = r >> 7, c = r & 127;
      w_bt[i] = bf16r(w[(o * C_ + c) * K2_ + kt]);
    }
  } else if (bid < 720) {
    int i = (bid - 576) * 256 + t;
    if (i < 32 * CK2_) {
      int f = i / CK2_, r = i % CK2_;
      int kt = r >> 7, c = r & 127;
      w_ot[i] = (f < F_) ? bf16r(w_off[f * CK2_ + c * K2_ + kt]) : (short)0;
    }
  } else {
    int xb_id = bid - 720;                 // 0..511
    int b = xb_id >> 6;
    int p_base = (xb_id & 63) << 6;
    const float* xb = x + ((long)b << 19);
#pragma unroll
    for (int i = 0; i < 32; ++i) {
      int idx = (i << 8) + t;
      int c = idx >> 6, p = idx & 63;
      tile[c][p] = xb[((long)c << 12) + p_base + p];
    }
    __syncthreads();
#pragma unroll
    for (int i = 0; i < 32; ++i) {
      int idx = (i << 8) + t;
      int p = idx >> 7, c = idx & 127;
      x_t[(((long)(b << 12) + p_base + p) << 7) + c] = bf16r(tile[c][p]);
    }
  }
}

// -------- fused kernel: 128 threads = 2 waves per block, 16 positions -------
// K-reduction split across waves: wave w handles c-chunks s in {w, w+2} of
// every tap (Phase A and B). Phase A partials summed at read; Phase B
// partials reduced through LDS by wave 0.
__global__ __launch_bounds__(128) void fused_deform_kernel(
    const short* __restrict__ x_t, const short* __restrict__ w_ot,
    const float* __restrict__ b_off, const short* __restrict__ w_bt,
    float* __restrict__ out) {
  __shared__ float offsA[2][16][20];     // per-wave partial offsets
  __shared__ float accL[16][132];        // wave-1 partial outputs [pos][o]

  int tid = threadIdx.x;
  int wv = tid >> 6;          // wave id: 0 or 1
  int lane = tid & 63;
  int fr = lane & 15;         // A: row sub ; B/D: position column
  int q  = lane >> 4;         // k-chunk selector within MFMA K=32
  int bid = (int)blockIdx.x;
  int swz = ((bid & 7) << 8) + (bid >> 3);   // XCD k <- batch k (2048 = 8*256)
  int pos_base = swz << 4;
  int b  = pos_base >> 12;
  int ho = (pos_base >> 6) & 63;
  int wo_base = pos_base & 63;
  int wo = wo_base + fr;

  const short* xtb = x_t + ((long)b << 19);

  // ---------------- Phase A: offset conv via MFMA (K-split) ----------------
  {
    f32x4_t oacc0 = (f32x4_t){0.f, 0.f, 0.f, 0.f};
    f32x4_t oacc1 = (f32x4_t){0.f, 0.f, 0.f, 0.f};
    for (int kt = 0; kt < 9; ++kt) {
      int y  = ho + kt / 3 - 1;
      int xx = wo + kt % 3 - 1;
      bool ok = (y >= 0) & (y < H_) & (xx >= 0) & (xx < W_);
      int yc = min(max(y, 0), H_ - 1), xc = min(max(xx, 0), W_ - 1);
      const short* px = xtb + (((yc << 6) + xc) << 7);
#pragma unroll
      for (int sh = 0; sh < 2; ++sh) {
        int s = (sh << 1) | wv;
        int c0 = (s << 5) + (q << 3);
        short8_t bfv = *(const short8_t*)(px + c0);
        if (!ok) bfv = (short8_t){0, 0, 0, 0, 0, 0, 0, 0};
        int kk = kt * 128 + c0;
        short8_t a0 = *(const short8_t*)(w_ot + fr * CK2_ + kk);
        short8_t a1 = *(const short8_t*)(w_ot + (16 + fr) * CK2_ + kk);
        oacc0 = __builtin_amdgcn_mfma_f32_16x16x32_bf16(a0, bfv, oacc0, 0, 0, 0);
        oacc1 = __builtin_amdgcn_mfma_f32_16x16x32_bf16(a1, bfv, oacc1, 0, 0, 0);
      }
    }
#pragma unroll
    for (int r = 0; r < 4; ++r) {
      int f0 = (q << 2) + r;
      offsA[wv][fr][f0] = oacc0[r] + (wv == 0 ? b_off[f0] : 0.f);
    }
    if (q == 0) {
      offsA[wv][fr][16] = oacc1[0] + (wv == 0 ? b_off[16] : 0.f);
      offsA[wv][fr][17] = oacc1[1] + (wv == 0 ? b_off[17] : 0.f);
    }
  }
  __syncthreads();

  // ---------------- Phase B: sampling + main GEMM (K-split) ----------------
  f32x4_t acc[8];
#pragma unroll
  for (int nf = 0; nf < 8; ++nf) acc[nf] = (f32x4_t){0.f, 0.f, 0.f, 0.f};

  for (int kt = 0; kt < 9; ++kt) {
    float oy = offsA[0][fr][2 * kt]     + offsA[1][fr][2 * kt];
    float ox = offsA[0][fr][2 * kt + 1] + offsA[1][fr][2 * kt + 1];
    float py = (float)(ho + (kt / 3) - 1) + oy;
    float px = (float)(wo + (kt % 3) - 1) + ox;
    float fy0 = floorf(py), fx0 = floorf(px);
    float dy = py - fy0, dx = px - fx0;
    int y0 = (int)fy0, x0 = (int)fx0;
    int y1 = y0 + 1, x1 = x0 + 1;
    float my0 = (y0 >= 0 && y0 < H_) ? 1.f : 0.f;
    float my1 = (y1 >= 0 && y1 < H_) ? 1.f : 0.f;
    float mx0 = (x0 >= 0 && x0 < W_) ? 1.f : 0.f;
    float mx1 = (x1 >= 0 && x1 < W_) ? 1.f : 0.f;
    float w00 = (1.f - dy) * (1.f - dx) * my0 * mx0;
    float w01 = (1.f - dy) * dx * my0 * mx1;
    float w10 = dy * (1.f - dx) * my1 * mx0;
    float w11 = dy * dx * my1 * mx1;
    int y0c = min(max(y0, 0), H_ - 1), y1c = min(max(y1, 0), H_ - 1);
    int x0c = min(max(x0, 0), W_ - 1), x1c = min(max(x1, 0), W_ - 1);
    const short* p00 = xtb + (((y0c << 6) + x0c) << 7);
    const short* p01 = xtb + (((y0c << 6) + x1c) << 7);
    const short* p10 = xtb + (((y1c << 6) + x0c) << 7);
    const short* p11 = xtb + (((y1c << 6) + x1c) << 7);

#pragma unroll
    for (int sh = 0; sh < 2; ++sh) {
      int s = (sh << 1) | wv;
      int c0 = (s << 5) + (q << 3);
      short8_t v00 = *(const short8_t*)(p00 + c0);
      short8_t v01 = *(const short8_t*)(p01 + c0);
      short8_t v10 = *(const short8_t*)(p10 + c0);
      short8_t v11 = *(const short8_t*)(p11 + c0);
      short8_t sf;
#pragma unroll
      for (int j = 0; j < 8; ++j) {
        float v = w00 * bf2f(v00[j]) + w01 * bf2f(v01[j]) +
                  w10 * bf2f(v10[j]) + w11 * bf2f(v11[j]);
        sf[j] = bf16r(v);
      }
      int kk = kt * 128 + c0;
      const short* wp = w_bt + fr * CK2_ + kk;
#pragma unroll
      for (int nf = 0; nf < 8; ++nf) {
        short8_t wf = *(const short8_t*)(wp + nf * 16 * CK2_);
        acc[nf] = __builtin_amdgcn_mfma_f32_16x16x32_bf16(wf, sf, acc[nf], 0, 0, 0);
      }
    }
  }

  // ---------------- reduce wave partials, store ----------------
  if (wv == 1) {
#pragma unroll
    for (int nf = 0; nf < 8; ++nf) {
      *(f32x4_t*)&accL[fr][(nf << 4) + (q << 2)] = acc[nf];
    }
  }
  __syncthreads();
  if (wv == 0) {
    float* ob = out + ((long)b * O_ * HW_) + (ho << 6) + wo_base + fr;
#pragma unroll
    for (int nf = 0; nf < 8; ++nf) {
      f32x4_t other = *(const f32x4_t*)&accL[fr][(nf << 4) + (q << 2)];
#pragma unroll
      for (int r = 0; r < 4; ++r) {
        ob[(((nf << 4) + (q << 2) + r) << 12)] = acc[nf][r] + other[r];
      }
    }
  }
}

extern "C" void kernel_launch(void* const* d_in, const int* in_sizes, int n_in,
                              void* d_out, int out_size, void* d_ws, size_t ws_size,
                              hipStream_t stream) {
  const float* x     = (const float*)d_in[0];
  const float* w_off = (const float*)d_in[1];
  const float* b_off = (const float*)d_in[2];
  const float* w     = (const float*)d_in[3];
  float* out = (float*)d_out;

  short* w_bt = (short*)d_ws;                                   // 294912 B
  short* w_ot = (short*)((char*)d_ws + 294912);                 // 73728 B
  short* x_t  = (short*)((char*)d_ws + 294912 + 73728);         // 8388608 B

  prep_all_kernel<<<1232, 256, 0, stream>>>(w, w_off, x, w_bt, w_ot, x_t);
  fused_deform_kernel<<<2048, 128, 0, stream>>>(x_t, w_ot, b_off, w_bt, out);
}

// Round 6
// 61.905 us; speedup vs baseline: 2.3687x; 2.3687x over previous
//
#include <hip/hip_runtime.h>

#define B_ 8
#define C_ 128
#define H_ 64
#define W_ 64
#define O_ 128
#define F_ 18
#define K2_ 9
#define HW_ 4096
#define CK2_ 1152

typedef __attribute__((ext_vector_type(8))) short short8_t;   // 8 bf16
typedef __attribute__((ext_vector_type(4))) float f32x4_t;

__device__ inline short bf16r(float f) {
  unsigned u = __builtin_bit_cast(unsigned, f);
  u += 0x7FFFu + ((u >> 16) & 1u);     // round-to-nearest-even
  return (short)(u >> 16);
}
__device__ inline float bf2f(short s) {
  unsigned u = ((unsigned)(unsigned short)s) << 16;
  return __builtin_bit_cast(float, u);
}

// ---------------- merged prep ----------------
// blocks [0,576):   w -> w_bt2[ks][o][kk2]  (ks=kt*4+s, c=(ks&3)*32+kk2)
// blocks [576,720): w_off -> w_ot2[ks][f32][kk2] (rows 18..31 zero)
// blocks [720,1232): x NCHW f32 -> x_t[b][y][x][c] bf16
__global__ __launch_bounds__(256) void prep_all_kernel(
    const float* __restrict__ w, const float* __restrict__ w_off,
    const float* __restrict__ x,
    short* __restrict__ w_bt2, short* __restrict__ w_ot2,
    short* __restrict__ x_t) {
  __shared__ float tile[128][65];
  int bid = blockIdx.x, t = threadIdx.x;
  if (bid < 576) {
    int i = bid * 256 + t;               // 0..147455 exact
    int kk2 = i & 31, o = (i >> 5) & 127, ks = i >> 12;
    w_bt2[i] = bf16r(w[(o * C_ + (ks & 3) * 32 + kk2) * K2_ + (ks >> 2)]);
  } else if (bid < 720) {
    int i = (bid - 576) * 256 + t;       // 0..36863 exact
    int kk2 = i & 31, f = (i >> 5) & 31, ks = i >> 10;
    w_ot2[i] = (f < F_) ? bf16r(w_off[(f * C_ + (ks & 3) * 32 + kk2) * K2_ + (ks >> 2)])
                        : (short)0;
  } else {
    int xb_id = bid - 720;               // 0..511
    int b = xb_id >> 6;
    int p_base = (xb_id & 63) << 6;
    const float* xb = x + ((long)b << 19);
#pragma unroll
    for (int i = 0; i < 32; ++i) {
      int idx = (i << 8) + t;
      int c = idx >> 6, p = idx & 63;
      tile[c][p] = xb[((long)c << 12) + p_base + p];
    }
    __syncthreads();
#pragma unroll
    for (int i = 0; i < 32; ++i) {
      int idx = (i << 8) + t;
      int p = idx >> 7, c = idx & 127;
      x_t[(((long)(b << 12) + p_base + p) << 7) + c] = bf16r(tile[c][p]);
    }
  }
}

// LDS chunk read: pixel-row 256B, 16B chunks XOR-swizzled by pix&7
__device__ inline short8_t lds16(const short* xs, int pix, int ch) {
  return *(const short8_t*)(xs + (pix << 7) + ((ch ^ (pix & 7)) << 3));
}

// ---------------- fused kernel ----------------
// block = 512 threads (8 waves), one 2-row strip = 128 positions of one batch.
// Stage x rows [ho0-3, ho0+4] (<=8) into 128KB LDS (swizzled). Each wave owns
// 16 positions, full K: Phase A offset conv (2 MFMA tiles), offsets
// redistributed via shfl; Phase B bilinear blend from LDS + 8-tile MFMA GEMM.
__global__ __launch_bounds__(512, 2) void fused_deform_kernel(
    const short* __restrict__ x_t, const short* __restrict__ w_ot2,
    const float* __restrict__ b_off, const short* __restrict__ w_bt2,
    float* __restrict__ out) {
  __shared__ short xs[8 * 64 * 128];     // 128 KB

  int tid = threadIdx.x;
  int wv = tid >> 6, lane = tid & 63;
  int fr = lane & 15, q = lane >> 4;
  int bid = (int)blockIdx.x;
  int b = bid & 7;                       // batch per XCD
  int strip = bid >> 3;                  // 0..31
  int ho0 = strip << 1;
  int ys = max(ho0 - 3, 0), ye = min(ho0 + 4, H_ - 1);

  const short* xtb = x_t + ((long)b << 19);

  // -------- stage x window --------
#pragma unroll
  for (int i = 0; i < 16; ++i) {
    int ci = (i << 9) + tid;             // 0..8191 chunk ids
    int pix = ci >> 4, ch = ci & 15;
    int y = ys + (pix >> 6);
    if (y <= ye) {
      short8_t v = *(const short8_t*)(xtb + (((y << 6) + (pix & 63)) << 7) + (ch << 3));
      *(short8_t*)(xs + (pix << 7) + ((ch ^ (pix & 7)) << 3)) = v;
    }
  }
  __syncthreads();

  int pos_l = (wv << 4) + fr;            // 0..127
  int row_l = pos_l >> 6;
  int wo = pos_l & 63;
  int ho = ho0 + row_l;

  // -------- Phase A: offset conv via MFMA --------
  f32x4_t oacc0 = (f32x4_t){0.f, 0.f, 0.f, 0.f};
  f32x4_t oacc1 = (f32x4_t){0.f, 0.f, 0.f, 0.f};
#pragma unroll
  for (int kt = 0; kt < 9; ++kt) {
    int y = ho + kt / 3 - 1, xx = wo + kt % 3 - 1;
    bool ok = (y >= 0) & (y < H_) & (xx >= 0) & (xx < W_);
    int yc = min(max(y, 0), H_ - 1), xc = min(max(xx, 0), W_ - 1);
    int pixA = ((yc - ys) << 6) + xc;
#pragma unroll
    for (int s = 0; s < 4; ++s) {
      short8_t bfv = lds16(xs, pixA, (s << 2) + q);
      if (!ok) bfv = (short8_t){0, 0, 0, 0, 0, 0, 0, 0};
      int ks = (kt << 2) + s;
      short8_t a0 = *(const short8_t*)(w_ot2 + (((ks << 5) + fr) << 5) + (q << 3));
      short8_t a1 = *(const short8_t*)(w_ot2 + (((ks << 5) + 16 + fr) << 5) + (q << 3));
      oacc0 = __builtin_amdgcn_mfma_f32_16x16x32_bf16(a0, bfv, oacc0, 0, 0, 0);
      oacc1 = __builtin_amdgcn_mfma_f32_16x16x32_bf16(a1, bfv, oacc1, 0, 0, 0);
    }
  }
  // D[f][pos]: offsets for position fr, f-group g live in lane fr+16g.

  // -------- Phase B: sampling + main GEMM --------
  f32x4_t acc[8];
#pragma unroll
  for (int nf = 0; nf < 8; ++nf) acc[nf] = (f32x4_t){0.f, 0.f, 0.f, 0.f};

#pragma unroll
  for (int kt = 0; kt < 9; ++kt) {
    float oy, ox;
    if (kt < 8) {
      oy = __shfl(oacc0[(2 * kt) & 3], fr + ((kt >> 1) << 4), 64);
      ox = __shfl(oacc0[(2 * kt + 1) & 3], fr + ((kt >> 1) << 4), 64);
    } else {
      oy = __shfl(oacc1[0], fr, 64);
      ox = __shfl(oacc1[1], fr, 64);
    }
    oy += b_off[2 * kt];
    ox += b_off[2 * kt + 1];

    float py = (float)(ho + kt / 3 - 1) + oy;
    float px = (float)(wo + kt % 3 - 1) + ox;
    float fy0 = floorf(py), fx0 = floorf(px);
    float dy = py - fy0, dx = px - fx0;
    int y0 = (int)fy0, x0 = (int)fx0;
    int y1 = y0 + 1, x1 = x0 + 1;
    float my0 = (y0 >= 0 && y0 < H_) ? 1.f : 0.f;
    float my1 = (y1 >= 0 && y1 < H_) ? 1.f : 0.f;
    float mx0 = (x0 >= 0 && x0 < W_) ? 1.f : 0.f;
    float mx1 = (x1 >= 0 && x1 < W_) ? 1.f : 0.f;
    float w00 = (1.f - dy) * (1.f - dx) * my0 * mx0;
    float w01 = (1.f - dy) * dx * my0 * mx1;
    float w10 = dy * (1.f - dx) * my1 * mx0;
    float w11 = dy * dx * my1 * mx1;
    int y0c = min(max(y0, 0), H_ - 1), y1c = min(max(y1, 0), H_ - 1);
    int x0c = min(max(x0, 0), W_ - 1), x1c = min(max(x1, 0), W_ - 1);
    int p00 = ((y0c - ys) << 6) + x0c, p01 = ((y0c - ys) << 6) + x1c;
    int p10 = ((y1c - ys) << 6) + x0c, p11 = ((y1c - ys) << 6) + x1c;

    short8_t v00[4], v01[4], v10[4], v11[4];
    unsigned long long bad = __ballot((y0c < ys) || (y1c > ye));
    if (bad == 0ULL) {
#pragma unroll
      for (int s = 0; s < 4; ++s) {
        int ch = (s << 2) + q;
        v00[s] = lds16(xs, p00, ch);
        v01[s] = lds16(xs, p01, ch);
        v10[s] = lds16(xs, p10, ch);
        v11[s] = lds16(xs, p11, ch);
      }
    } else {                             // rare fallback: global gathers
      const short* g00 = xtb + (((y0c << 6) + x0c) << 7);
      const short* g01 = xtb + (((y0c << 6) + x1c) << 7);
      const short* g10 = xtb + (((y1c << 6) + x0c) << 7);
      const short* g11 = xtb + (((y1c << 6) + x1c) << 7);
#pragma unroll
      for (int s = 0; s < 4; ++s) {
        int c0 = (s << 5) + (q << 3);
        v00[s] = *(const short8_t*)(g00 + c0);
        v01[s] = *(const short8_t*)(g01 + c0);
        v10[s] = *(const short8_t*)(g10 + c0);
        v11[s] = *(const short8_t*)(g11 + c0);
      }
    }

#pragma unroll
    for (int s = 0; s < 4; ++s) {
      short8_t sf;
#pragma unroll
      for (int j = 0; j < 8; ++j) {
        float v = w00 * bf2f(v00[s][j]) + w01 * bf2f(v01[s][j]) +
                  w10 * bf2f(v10[s][j]) + w11 * bf2f(v11[s][j]);
        sf[j] = bf16r(v);
      }
      int ks = (kt << 2) + s;
      const short* wp = w_bt2 + (((ks << 7) + fr) << 5) + (q << 3);
#pragma unroll
      for (int nf = 0; nf < 8; ++nf) {
        short8_t wf = *(const short8_t*)(wp + (nf << 9));   // +nf*16 rows
        acc[nf] = __builtin_amdgcn_mfma_f32_16x16x32_bf16(wf, sf, acc[nf], 0, 0, 0);
      }
    }
  }

  // -------- epilogue: D[o][pos], coalesced over fr --------
  float* ob = out + ((long)(b * O_) << 12) + (ho << 6) + wo;
#pragma unroll
  for (int nf = 0; nf < 8; ++nf) {
#pragma unroll
    for (int r = 0; r < 4; ++r) {
      ob[(long)(((nf << 4) + (q << 2) + r)) << 12] = acc[nf][r];
    }
  }
}

extern "C" void kernel_launch(void* const* d_in, const int* in_sizes, int n_in,
                              void* d_out, int out_size, void* d_ws, size_t ws_size,
                              hipStream_t stream) {
  const float* x     = (const float*)d_in[0];
  const float* w_off = (const float*)d_in[1];
  const float* b_off = (const float*)d_in[2];
  const float* w     = (const float*)d_in[3];
  float* out = (float*)d_out;

  short* w_bt2 = (short*)d_ws;                                  // 294912 B
  short* w_ot2 = (short*)((char*)d_ws + 294912);                // 73728 B
  short* x_t   = (short*)((char*)d_ws + 294912 + 73728);        // 8388608 B

  prep_all_kernel<<<1232, 256, 0, stream>>>(w, w_off, x, w_bt2, w_ot2, x_t);
  fused_deform_kernel<<<256, 512, 0, stream>>>(x_t, w_ot2, b_off, w_bt2, out);
}